// Round 4
// baseline (316.311 us; speedup 1.0000x reference)
//
#include <hip/hip_runtime.h>

#define NB 8
#define CH 256
#define NT 2304
#define KVSPLIT 3
#define TPS 12  // kv tiles of 64 per split
#define QB 128  // q rows per block
#define ATTN_SCALE 0.17677669529663687f
#define LN_EPS 1e-6f

typedef __attribute__((ext_vector_type(8))) short short8;
typedef __attribute__((ext_vector_type(4))) float f32x4;
typedef __attribute__((ext_vector_type(16))) float f32x16;
typedef __attribute__((ext_vector_type(4))) unsigned short ushort4v;
typedef __attribute__((ext_vector_type(8))) unsigned short ushort8v;
typedef __attribute__((ext_vector_type(4))) float float4v;

__device__ __forceinline__ unsigned short f2bf(float f) {
  unsigned int u = __float_as_uint(f);
  u += 0x7fffu + ((u >> 16) & 1u);
  return (unsigned short)(u >> 16);
}
__device__ __forceinline__ float bf2f(unsigned short s) {
  return __uint_as_float(((unsigned int)s) << 16);
}
__device__ __forceinline__ unsigned int cvtpk(float a, float b) {
  unsigned int r;
  asm("v_cvt_pk_bf16_f32 %0, %1, %2" : "=v"(r) : "v"(a), "v"(b));
  return r;
}

__device__ __forceinline__ void gload_lds16(const void* g, void* l) {
  __builtin_amdgcn_global_load_lds(
      (const __attribute__((address_space(1))) unsigned int*)g,
      (__attribute__((address_space(3))) unsigned int*)l, 16, 0, 0);
}

// ---------------- weight fp32 -> bf16 convert ----------------
__global__ __launch_bounds__(256) void wconv_kernel(
    const float* __restrict__ wq, const float* __restrict__ wk,
    const float* __restrict__ wv, const float* __restrict__ wp,
    unsigned short* __restrict__ out) {
  int z = blockIdx.y;
  const float* src = (z == 0) ? wq : (z == 1) ? wk : (z == 2) ? wv : wp;
  unsigned short* dst = out + z * 65536;
  int i = (blockIdx.x * 256 + threadIdx.x) * 4;
  float4v v = *(const float4v*)(src + i);
  ushort4v r;
  r[0] = f2bf(v[0]); r[1] = f2bf(v[1]); r[2] = f2bf(v[2]); r[3] = f2bf(v[3]);
  *(ushort4v*)(dst + i) = r;
}

// ---------------- channel LayerNorm + transpose to [B,N,C] bf16 (x1 & x2 fused) ----
__global__ __launch_bounds__(256) void ln_kernel(
    const float* __restrict__ x1, const float* __restrict__ x2,
    const float* __restrict__ w1, const float* __restrict__ b1,
    const float* __restrict__ w2, const float* __restrict__ b2,
    unsigned short* __restrict__ o1, unsigned short* __restrict__ o2) {
  __shared__ float part[4][64][2];
  __shared__ float fin[64][2];
  int z = blockIdx.z;
  const float* x = z ? x2 : x1;
  const float* w = z ? w2 : w1;
  const float* bias = z ? b2 : b1;
  unsigned short* out = z ? o2 : o1;
  int tid = threadIdx.x;
  int lane = tid & 63, wv = tid >> 6;
  int n0 = blockIdx.x * 64;
  int b = blockIdx.y;
  const float* xp = x + (size_t)b * CH * NT + n0 + lane;
  float xc[64];
  float sum = 0.f, ss = 0.f;
#pragma unroll
  for (int j = 0; j < 64; ++j) {
    float v = xp[(size_t)(wv * 64 + j) * NT];
    xc[j] = v;
    sum += v; ss += v * v;
  }
  part[wv][lane][0] = sum;
  part[wv][lane][1] = ss;
  __syncthreads();
  if (tid < 64) {
    float s = 0.f, q = 0.f;
#pragma unroll
    for (int wi = 0; wi < 4; ++wi) { s += part[wi][tid][0]; q += part[wi][tid][1]; }
    float u = s * (1.0f / CH);
    float var = q * (1.0f / CH) - u * u;
    fin[tid][0] = u;
    fin[tid][1] = rsqrtf(var + LN_EPS);
  }
  __syncthreads();
  float u = fin[lane][0], rstd = fin[lane][1];
  unsigned short* op = out + ((size_t)b * NT + n0 + lane) * CH;
#pragma unroll
  for (int c0 = 0; c0 < 64; c0 += 8) {
    ushort8v pk;
#pragma unroll
    for (int j = 0; j < 8; ++j)
      pk[j] = f2bf((xc[c0 + j] - u) * rstd * w[wv * 64 + c0 + j] +
                   bias[wv * 64 + c0 + j]);
    *(ushort8v*)(op + wv * 64 + c0) = pk;
  }
}

// ---------------- QKV projection GEMM (128x128, BK=64, 4 waves) ----------------
__global__ __launch_bounds__(256) void proj_kernel(
    const unsigned short* __restrict__ xq, const unsigned short* __restrict__ xkv,
    const unsigned short* __restrict__ wbf,
    const float* __restrict__ bq, const float* __restrict__ bk,
    const float* __restrict__ bv,
    unsigned short* __restrict__ q, unsigned short* __restrict__ k,
    unsigned short* __restrict__ vt) {
  __shared__ char As[16384];
  __shared__ char Bs[16384];
  int tid = threadIdx.x;
  int lane = tid & 63, wid = tid >> 6;
  int z = blockIdx.z;
  int b = z / 3, pz = z - b * 3;
  const unsigned short* A = ((pz == 0) ? xq : xkv) + (size_t)b * NT * CH;
  const unsigned short* W = wbf + pz * 65536;
  const float* bias = (pz == 0) ? bq : (pz == 1) ? bk : bv;
  int m0 = blockIdx.x * 128;
  int c0 = blockIdx.y * 128;
  int wr = wid >> 1, wc = wid & 1;

  f32x4 zero4 = {0.f, 0.f, 0.f, 0.f};
  f32x4 acc[4][4];
#pragma unroll
  for (int i = 0; i < 4; ++i)
#pragma unroll
    for (int j = 0; j < 4; ++j) acc[i][j] = zero4;

  for (int kt = 0; kt < 4; ++kt) {
#pragma unroll
    for (int it = 0; it < 4; ++it) {
      int li = it * 256 + tid;
      int X = li * 16;
      int row = X >> 7;
      int colb = (X & 127) ^ ((row & 7) << 4);
      gload_lds16((const char*)A + ((size_t)(m0 + row) * CH + kt * 64) * 2 + colb,
                  As + it * 4096 + wid * 1024);
      gload_lds16((const char*)W + ((size_t)(c0 + row) * CH + kt * 64) * 2 + colb,
                  Bs + it * 4096 + wid * 1024);
    }
    __syncthreads();
#pragma unroll
    for (int kk = 0; kk < 2; ++kk) {
      int cb = kk * 64 + ((lane >> 4) << 4);
      short8 af[4], bf[4];
#pragma unroll
      for (int mi = 0; mi < 4; ++mi) {
        int row = wr * 64 + mi * 16 + (lane & 15);
        af[mi] = *(const short8*)(As + row * 128 + (cb ^ ((row & 7) << 4)));
      }
#pragma unroll
      for (int ni = 0; ni < 4; ++ni) {
        int row = wc * 64 + ni * 16 + (lane & 15);
        bf[ni] = *(const short8*)(Bs + row * 128 + (cb ^ ((row & 7) << 4)));
      }
#pragma unroll
      for (int mi = 0; mi < 4; ++mi)
#pragma unroll
        for (int ni = 0; ni < 4; ++ni)
          acc[mi][ni] = __builtin_amdgcn_mfma_f32_16x16x32_bf16(
              af[mi], bf[ni], acc[mi][ni], 0, 0, 0);
    }
    __syncthreads();
  }

  int colbase = c0 + wc * 64;
  int rowbase = m0 + wr * 64;
  if (pz < 2) {
    unsigned short* dst = ((pz == 0) ? q : k) + (size_t)b * NT * CH;
    float scl = (pz == 0) ? ATTN_SCALE : 1.0f;
#pragma unroll
    for (int mi = 0; mi < 4; ++mi)
#pragma unroll
      for (int ni = 0; ni < 4; ++ni) {
        int col = colbase + ni * 16 + (lane & 15);
        float bb = bias[col];
        int row0 = rowbase + mi * 16 + ((lane >> 4) << 2);
#pragma unroll
        for (int r = 0; r < 4; ++r)
          dst[(size_t)(row0 + r) * CH + col] = f2bf((acc[mi][ni][r] + bb) * scl);
      }
  } else {
    unsigned short* dst = vt + (size_t)b * CH * NT;
#pragma unroll
    for (int mi = 0; mi < 4; ++mi)
#pragma unroll
      for (int ni = 0; ni < 4; ++ni) {
        int col = colbase + ni * 16 + (lane & 15);
        float bb = bias[col];
        int row0 = rowbase + mi * 16 + ((lane >> 4) << 2);
        ushort4v pk;
#pragma unroll
        for (int r = 0; r < 4; ++r) pk[r] = f2bf(acc[mi][ni][r] + bb);
        *(ushort4v*)(dst + (size_t)col * NT + row0) = pk;
      }
  }
}

// ---------------- flash attention v4: 32x32 MFMA, q=32/wave, zero-LDS P ------
// S^T = K·Q (A=K rows=kv, B=Q cols=q=lane&31). Softmax in-lane per q.
// P B-frags = cvt_pk of S accumulator regs (kv-permutation applied equally
// to V A-frags). O^T = V^T·P accumulated [256d][32q] in regs. K dbuf in LDS.
__global__ __launch_bounds__(256, 2) void attn_kernel(
    const unsigned short* __restrict__ q, const unsigned short* __restrict__ k,
    const unsigned short* __restrict__ vt,
    unsigned short* __restrict__ op0, unsigned short* __restrict__ op1,
    unsigned short* __restrict__ op2, float* __restrict__ ml) {
  __shared__ char Ks[2][32768];  // [64 kv][256 ch] bf16, XOR-swizzled
  int tid = threadIdx.x, lane = tid & 63, wid = tid >> 6;
  int r31 = lane & 31, h2 = lane >> 5;
  int b = blockIdx.z;
  int split = blockIdx.y;
  int q0 = blockIdx.x * QB;
  const unsigned short* qb_ = q + (size_t)b * NT * CH;
  const unsigned short* kb = k + (size_t)b * NT * CH;
  const unsigned short* vbase = vt + (size_t)b * CH * NT + (size_t)r31 * NT;

  // Q B-fragments: 32 q-rows x 256 ch per wave (col=q=lane&31, k=h2*8+j)
  int qrow = q0 + wid * 32 + r31;
  short8 qf[16];
#pragma unroll
  for (int st = 0; st < 16; ++st)
    qf[st] = *(const short8*)(qb_ + (size_t)qrow * CH + st * 16 + h2 * 8);

  f32x16 o[8];
#pragma unroll
  for (int i = 0; i < 8; ++i) o[i] = (f32x16){};
  float mrun = -INFINITY, lrun = 0.f;

  int kt0base = split * TPS * 64;
  // prologue: stage K tile 0
#pragma unroll
  for (int it = 0; it < 8; ++it) {
    int X = (it * 256 + tid) * 16;
    int row = X >> 9;
    int colb = (X & 511) ^ ((row & 7) << 4);
    gload_lds16((const char*)kb + ((size_t)(kt0base + row) * CH) * 2 + colb,
                Ks[0] + it * 4096 + wid * 1024);
  }
  __syncthreads();

  union V8 { struct { ushort4v a, b; } h; short8 s8; };
  union PB { unsigned int u[4]; short8 s8; };

  for (int t = 0; t < TPS; ++t) {
    int kt0 = kt0base + t * 64;
    const char* kbase = Ks[t & 1];
    // stage next K tile (in flight across whole tile's compute)
    if (t + 1 < TPS) {
#pragma unroll
      for (int it = 0; it < 8; ++it) {
        int X = (it * 256 + tid) * 16;
        int row = X >> 9;
        int colb = (X & 511) ^ ((row & 7) << 4);
        gload_lds16((const char*)kb + ((size_t)(kt0 + 64 + row) * CH) * 2 + colb,
                    Ks[(t + 1) & 1] + it * 4096 + wid * 1024);
      }
    }

    // S^T = K Q : two 32-kv tiles, 16 k-steps of 16 ch
    f32x16 s0 = (f32x16){}, s1 = (f32x16){};
    __builtin_amdgcn_s_setprio(1);
#pragma unroll
    for (int st = 0; st < 16; ++st) {
      int cb = (st * 32 + h2 * 16);
      short8 kf0 = *(const short8*)(kbase + r31 * 512 + (cb ^ ((r31 & 7) << 4)));
      s0 = __builtin_amdgcn_mfma_f32_32x32x16_bf16(kf0, qf[st], s0, 0, 0, 0);
      int row1 = 32 + r31;
      short8 kf1 = *(const short8*)(kbase + row1 * 512 + (cb ^ ((row1 & 7) << 4)));
      s1 = __builtin_amdgcn_mfma_f32_32x32x16_bf16(kf1, qf[st], s1, 0, 0, 0);
    }
    __builtin_amdgcn_s_setprio(0);

    // in-lane online softmax for q = lane&31 (pair lane, lane^32 covers kv 64)
    float mx = -INFINITY;
#pragma unroll
    for (int i = 0; i < 16; ++i) mx = fmaxf(mx, fmaxf(s0[i], s1[i]));
    mx = fmaxf(mx, __shfl_xor(mx, 32));
    if (__any(mx - mrun > 8.0f)) {  // T13 defer-max
      float mnew = fmaxf(mrun, mx);
      float al = __expf(mrun - mnew);
      lrun *= al;
      mrun = mnew;
#pragma unroll
      for (int i = 0; i < 8; ++i) o[i] = o[i] * al;
    }
    float rs = 0.f;
#pragma unroll
    for (int i = 0; i < 16; ++i) {
      s0[i] = __expf(s0[i] - mrun); rs += s0[i];
      s1[i] = __expf(s1[i] - mrun); rs += s1[i];
    }
    rs += __shfl_xor(rs, 32);
    lrun += rs;

    // P B-frags: packs of S regs in order (kv-permutation folded into V)
    PB pb00, pb01, pb10, pb11;
    pb00.u[0] = cvtpk(s0[0], s0[1]);   pb00.u[1] = cvtpk(s0[2], s0[3]);
    pb00.u[2] = cvtpk(s0[4], s0[5]);   pb00.u[3] = cvtpk(s0[6], s0[7]);
    pb01.u[0] = cvtpk(s0[8], s0[9]);   pb01.u[1] = cvtpk(s0[10], s0[11]);
    pb01.u[2] = cvtpk(s0[12], s0[13]); pb01.u[3] = cvtpk(s0[14], s0[15]);
    pb10.u[0] = cvtpk(s1[0], s1[1]);   pb10.u[1] = cvtpk(s1[2], s1[3]);
    pb10.u[2] = cvtpk(s1[4], s1[5]);   pb10.u[3] = cvtpk(s1[6], s1[7]);
    pb11.u[0] = cvtpk(s1[8], s1[9]);   pb11.u[1] = cvtpk(s1[10], s1[11]);
    pb11.u[2] = cvtpk(s1[12], s1[13]); pb11.u[3] = cvtpk(s1[14], s1[15]);

    // O^T += V^T P  (A=V^T[32d][16kv], per-lane 2x b64 with kv perm 4h2+{0..3,8..11})
#define LOADV(dst, d2)                                                         \
    {                                                                          \
      const unsigned short* vr = vbase + (size_t)((d2) * 32) * NT + kt0;       \
      dst[0].h.a = *(const ushort4v*)(vr + 4 * h2);                            \
      dst[0].h.b = *(const ushort4v*)(vr + 4 * h2 + 8);                        \
      dst[1].h.a = *(const ushort4v*)(vr + 16 + 4 * h2);                       \
      dst[1].h.b = *(const ushort4v*)(vr + 16 + 4 * h2 + 8);                   \
      dst[2].h.a = *(const ushort4v*)(vr + 32 + 4 * h2);                       \
      dst[2].h.b = *(const ushort4v*)(vr + 32 + 4 * h2 + 8);                   \
      dst[3].h.a = *(const ushort4v*)(vr + 48 + 4 * h2);                       \
      dst[3].h.b = *(const ushort4v*)(vr + 48 + 4 * h2 + 8);                   \
    }
#define MFMA4(v, d2)                                                           \
    {                                                                          \
      o[d2] = __builtin_amdgcn_mfma_f32_32x32x16_bf16(v[0].s8, pb00.s8, o[d2], 0, 0, 0); \
      o[d2] = __builtin_amdgcn_mfma_f32_32x32x16_bf16(v[1].s8, pb01.s8, o[d2], 0, 0, 0); \
      o[d2] = __builtin_amdgcn_mfma_f32_32x32x16_bf16(v[2].s8, pb10.s8, o[d2], 0, 0, 0); \
      o[d2] = __builtin_amdgcn_mfma_f32_32x32x16_bf16(v[3].s8, pb11.s8, o[d2], 0, 0, 0); \
    }
    {
      V8 va[4], vb2[4];
      LOADV(va, 0);
#pragma unroll
      for (int d2 = 0; d2 < 8; d2 += 2) {
        LOADV(vb2, d2 + 1);
        __builtin_amdgcn_s_setprio(1);
        MFMA4(va, d2);
        __builtin_amdgcn_s_setprio(0);
        if (d2 < 6) LOADV(va, d2 + 2);
        __builtin_amdgcn_s_setprio(1);
        MFMA4(vb2, d2 + 1);
        __builtin_amdgcn_s_setprio(0);
      }
    }
    __syncthreads();  // drains stage (vmcnt0) + orders K buffer reuse
  }

  // store unnormalized partial O^T -> [B,N,C] rows, and (m,l)
  unsigned short* od = ((split == 0) ? op0 : (split == 1) ? op1 : op2) +
                       (size_t)(b * NT + qrow) * CH;
#pragma unroll
  for (int d2 = 0; d2 < 8; ++d2)
#pragma unroll
    for (int m = 0; m < 4; ++m) {
      ushort4v pk;
#pragma unroll
      for (int r = 0; r < 4; ++r) pk[r] = f2bf(o[d2][m * 4 + r]);
      *(ushort4v*)(od + d2 * 32 + m * 8 + h2 * 4) = pk;
    }
  if (lane < 32) {
    float* mlp = ml + ((size_t)(split * NB + b) * NT + q0 + wid * 32 + lane) * 2;
    mlp[0] = mrun;
    mlp[1] = lrun;
  }
}

// ---------------- combine 3 KV-split partials -> oa bf16 [B,N,C] ------------
__global__ __launch_bounds__(256) void combine_kernel(
    const unsigned short* __restrict__ op0, const unsigned short* __restrict__ op1,
    const unsigned short* __restrict__ op2, const float* __restrict__ ml,
    unsigned short* __restrict__ oa) {
  const size_t S = (size_t)NB * NT;
  int g = blockIdx.x * 8 + (threadIdx.x >> 5);
  int c = (threadIdx.x & 31) * 8;
  float m0 = ml[(size_t)g * 2], l0 = ml[(size_t)g * 2 + 1];
  float m1 = ml[(S + g) * 2], l1 = ml[(S + g) * 2 + 1];
  float m2 = ml[(2 * S + g) * 2], l2 = ml[(2 * S + g) * 2 + 1];
  float M = fmaxf(fmaxf(m0, m1), m2);
  float w0 = __expf(m0 - M), w1 = __expf(m1 - M), w2 = __expf(m2 - M);
  float Li = 1.0f / (w0 * l0 + w1 * l1 + w2 * l2);
  w0 *= Li; w1 *= Li; w2 *= Li;
  ushort8v a0 = *(const ushort8v*)(op0 + (size_t)g * CH + c);
  ushort8v a1 = *(const ushort8v*)(op1 + (size_t)g * CH + c);
  ushort8v a2 = *(const ushort8v*)(op2 + (size_t)g * CH + c);
  ushort8v r;
#pragma unroll
  for (int j = 0; j < 8; ++j)
    r[j] = f2bf(w0 * bf2f(a0[j]) + w1 * bf2f(a1[j]) + w2 * bf2f(a2[j]));
  *(ushort8v*)(oa + (size_t)g * CH + c) = r;
}

// ---------------- output projection + bias + residual, out [B,C,N] fp32 ----------------
__global__ __launch_bounds__(256) void oproj_kernel(
    const unsigned short* __restrict__ oa, const unsigned short* __restrict__ wp,
    const float* __restrict__ bp, const float* __restrict__ x1,
    float* __restrict__ outp) {
  __shared__ char As[16384];
  __shared__ char Bs[16384];
  int tid = threadIdx.x;
  int lane = tid & 63, wid = tid >> 6;
  int b = blockIdx.z;
  const unsigned short* A = oa + (size_t)b * NT * CH;
  int m0 = blockIdx.x * 128;
  int c0 = blockIdx.y * 128;
  int wr = wid >> 1, wc = wid & 1;

  f32x4 zero4 = {0.f, 0.f, 0.f, 0.f};
  f32x4 acc[4][4];
#pragma unroll
  for (int i = 0; i < 4; ++i)
#pragma unroll
    for (int j = 0; j < 4; ++j) acc[i][j] = zero4;

  for (int kt = 0; kt < 4; ++kt) {
#pragma unroll
    for (int it = 0; it < 4; ++it) {
      int li = it * 256 + tid;
      int X = li * 16;
      int row = X >> 7;
      int colb = (X & 127) ^ ((row & 7) << 4);
      gload_lds16((const char*)A + ((size_t)(m0 + row) * CH + kt * 64) * 2 + colb,
                  As + it * 4096 + wid * 1024);
      gload_lds16((const char*)wp + ((size_t)(c0 + row) * CH + kt * 64) * 2 + colb,
                  Bs + it * 4096 + wid * 1024);
    }
    __syncthreads();
#pragma unroll
    for (int kk = 0; kk < 2; ++kk) {
      int cb = kk * 64 + ((lane >> 4) << 4);
      short8 af[4], bf[4];
#pragma unroll
      for (int mi = 0; mi < 4; ++mi) {
        int row = wr * 64 + mi * 16 + (lane & 15);
        af[mi] = *(const short8*)(As + row * 128 + (cb ^ ((row & 7) << 4)));
      }
#pragma unroll
      for (int ni = 0; ni < 4; ++ni) {
        int row = wc * 64 + ni * 16 + (lane & 15);
        bf[ni] = *(const short8*)(Bs + row * 128 + (cb ^ ((row & 7) << 4)));
      }
#pragma unroll
      for (int mi = 0; mi < 4; ++mi)
#pragma unroll
        for (int ni = 0; ni < 4; ++ni)
          acc[mi][ni] = __builtin_amdgcn_mfma_f32_16x16x32_bf16(
              af[mi], bf[ni], acc[mi][ni], 0, 0, 0);
    }
    __syncthreads();
  }

  int colbase = c0 + wc * 64;
  int rowbase = m0 + wr * 64;
#pragma unroll
  for (int mi = 0; mi < 4; ++mi)
#pragma unroll
    for (int ni = 0; ni < 4; ++ni) {
      int col = colbase + ni * 16 + (lane & 15);
      float bb = bp[col];
      int row0 = rowbase + mi * 16 + ((lane >> 4) << 2);
      int base = (b * CH + col) * NT + row0;
      float4v xv = *(const float4v*)(x1 + base);
      float4v rs;
#pragma unroll
      for (int r = 0; r < 4; ++r) rs[r] = acc[mi][ni][r] + bb + xv[r];
      *(float4v*)(outp + base) = rs;
    }
}

extern "C" void kernel_launch(void* const* d_in, const int* in_sizes, int n_in,
                              void* d_out, int out_size, void* d_ws, size_t ws_size,
                              hipStream_t stream) {
  (void)in_sizes; (void)n_in; (void)out_size; (void)ws_size;
  const float* x1 = (const float*)d_in[0];
  const float* x2 = (const float*)d_in[1];
  const float* Wq = (const float*)d_in[2];
  const float* bq = (const float*)d_in[3];
  const float* Wk = (const float*)d_in[4];
  const float* bk = (const float*)d_in[5];
  const float* Wv = (const float*)d_in[6];
  const float* bv = (const float*)d_in[7];
  const float* Wp = (const float*)d_in[8];
  const float* bp = (const float*)d_in[9];
  const float* wnq = (const float*)d_in[10];
  const float* bnq = (const float*)d_in[11];
  const float* wnkv = (const float*)d_in[12];
  const float* bnkv = (const float*)d_in[13];
  float* outp = (float*)d_out;

  const size_t TSZ = (size_t)NB * NT * CH;  // 4718592 elements
  unsigned short* xq = (unsigned short*)d_ws;   // -> opart0 after proj
  unsigned short* xkv = xq + TSZ;               // -> opart1 after proj
  unsigned short* qb = xkv + TSZ;
  unsigned short* kbuf = qb + TSZ;
  unsigned short* vtb = kbuf + TSZ;
  unsigned short* oab = vtb + TSZ;              // opart2, combined in-place
  unsigned short* wbf = oab + TSZ;              // 4 x 65536
  float* ml = (float*)(wbf + 4 * 65536);        // KVSPLIT * NB * NT * 2 floats

  wconv_kernel<<<dim3(64, 4), dim3(256), 0, stream>>>(Wq, Wk, Wv, Wp, wbf);
  ln_kernel<<<dim3(36, 8, 2), dim3(256), 0, stream>>>(x1, x2, wnq, bnq, wnkv, bnkv,
                                                      xq, xkv);
  proj_kernel<<<dim3(18, 2, 24), dim3(256), 0, stream>>>(xq, xkv, wbf, bq, bk, bv,
                                                         qb, kbuf, vtb);
  attn_kernel<<<dim3(NT / QB, KVSPLIT, 8), dim3(256), 0, stream>>>(
      qb, kbuf, vtb, xq, xkv, oab, ml);
  combine_kernel<<<dim3(NB * NT / 8), dim3(256), 0, stream>>>(xq, xkv, oab, ml,
                                                              oab);
  oproj_kernel<<<dim3(18, 2, 8), dim3(256), 0, stream>>>(oab, wbf + 3 * 65536, bp,
                                                         x1, outp);
}

// Round 5
// 147.904 us; speedup vs baseline: 2.1386x; 2.1386x over previous
//
#include <hip/hip_runtime.h>

#define NB 8
#define CH 256
#define NT 2304
#define KVSPLIT 3
#define TPS 24  // kv tiles of 32 per split
#define QB 128  // q rows per block
#define QSCALE 0.2550349f       // (1/sqrt(64)) * log2(e)
#define DEFER_THR 11.5415604f   // 8 * log2(e)
#define LN_EPS 1e-6f

typedef __attribute__((ext_vector_type(8))) short short8;
typedef __attribute__((ext_vector_type(4))) float f32x4;
typedef __attribute__((ext_vector_type(16))) float f32x16;
typedef __attribute__((ext_vector_type(4))) unsigned short ushort4v;
typedef __attribute__((ext_vector_type(8))) unsigned short ushort8v;
typedef __attribute__((ext_vector_type(4))) float float4v;
typedef __attribute__((ext_vector_type(2))) unsigned int uint2v;

__device__ __forceinline__ unsigned short f2bf(float f) {
  unsigned int u = __float_as_uint(f);
  u += 0x7fffu + ((u >> 16) & 1u);
  return (unsigned short)(u >> 16);
}
__device__ __forceinline__ float bf2f(unsigned short s) {
  return __uint_as_float(((unsigned int)s) << 16);
}
__device__ __forceinline__ unsigned int cvtpk(float a, float b) {
  unsigned int r;
  asm("v_cvt_pk_bf16_f32 %0, %1, %2" : "=v"(r) : "v"(a), "v"(b));
  return r;
}

__device__ __forceinline__ void gload_lds16(const void* g, void* l) {
  __builtin_amdgcn_global_load_lds(
      (const __attribute__((address_space(1))) unsigned int*)g,
      (__attribute__((address_space(3))) unsigned int*)l, 16, 0, 0);
}

// ---------------- weight fp32 -> bf16 convert ----------------
__global__ __launch_bounds__(256) void wconv_kernel(
    const float* __restrict__ wq, const float* __restrict__ wk,
    const float* __restrict__ wv, const float* __restrict__ wp,
    unsigned short* __restrict__ out) {
  int z = blockIdx.y;
  const float* src = (z == 0) ? wq : (z == 1) ? wk : (z == 2) ? wv : wp;
  unsigned short* dst = out + z * 65536;
  int i = (blockIdx.x * 256 + threadIdx.x) * 4;
  float4v v = *(const float4v*)(src + i);
  ushort4v r;
  r[0] = f2bf(v[0]); r[1] = f2bf(v[1]); r[2] = f2bf(v[2]); r[3] = f2bf(v[3]);
  *(ushort4v*)(dst + i) = r;
}

// ---------------- channel LayerNorm + transpose to [B,N,C] bf16 (x1 & x2 fused) ----
__global__ __launch_bounds__(256) void ln_kernel(
    const float* __restrict__ x1, const float* __restrict__ x2,
    const float* __restrict__ w1, const float* __restrict__ b1,
    const float* __restrict__ w2, const float* __restrict__ b2,
    unsigned short* __restrict__ o1, unsigned short* __restrict__ o2) {
  __shared__ float part[4][64][2];
  __shared__ float fin[64][2];
  int z = blockIdx.z;
  const float* x = z ? x2 : x1;
  const float* w = z ? w2 : w1;
  const float* bias = z ? b2 : b1;
  unsigned short* out = z ? o2 : o1;
  int tid = threadIdx.x;
  int lane = tid & 63, wv = tid >> 6;
  int n0 = blockIdx.x * 64;
  int b = blockIdx.y;
  const float* xp = x + (size_t)b * CH * NT + n0 + lane;
  float xc[64];
  float sum = 0.f, ss = 0.f;
#pragma unroll
  for (int j = 0; j < 64; ++j) {
    float v = xp[(size_t)(wv * 64 + j) * NT];
    xc[j] = v;
    sum += v; ss += v * v;
  }
  part[wv][lane][0] = sum;
  part[wv][lane][1] = ss;
  __syncthreads();
  if (tid < 64) {
    float s = 0.f, q = 0.f;
#pragma unroll
    for (int wi = 0; wi < 4; ++wi) { s += part[wi][tid][0]; q += part[wi][tid][1]; }
    float u = s * (1.0f / CH);
    float var = q * (1.0f / CH) - u * u;
    fin[tid][0] = u;
    fin[tid][1] = rsqrtf(var + LN_EPS);
  }
  __syncthreads();
  float u = fin[lane][0], rstd = fin[lane][1];
  unsigned short* op = out + ((size_t)b * NT + n0 + lane) * CH;
#pragma unroll
  for (int c0 = 0; c0 < 64; c0 += 8) {
    ushort8v pk;
#pragma unroll
    for (int j = 0; j < 8; ++j)
      pk[j] = f2bf((xc[c0 + j] - u) * rstd * w[wv * 64 + c0 + j] +
                   bias[wv * 64 + c0 + j]);
    *(ushort8v*)(op + wv * 64 + c0) = pk;
  }
}

// ---------------- QKV projection GEMM (128x128, BK=64, 4 waves) ----------------
__global__ __launch_bounds__(256) void proj_kernel(
    const unsigned short* __restrict__ xq, const unsigned short* __restrict__ xkv,
    const unsigned short* __restrict__ wbf,
    const float* __restrict__ bq, const float* __restrict__ bk,
    const float* __restrict__ bv,
    unsigned short* __restrict__ q, unsigned short* __restrict__ k,
    unsigned short* __restrict__ vt) {
  __shared__ char As[16384];
  __shared__ char Bs[16384];
  int tid = threadIdx.x;
  int lane = tid & 63, wid = tid >> 6;
  int z = blockIdx.z;
  int b = z / 3, pz = z - b * 3;
  const unsigned short* A = ((pz == 0) ? xq : xkv) + (size_t)b * NT * CH;
  const unsigned short* W = wbf + pz * 65536;
  const float* bias = (pz == 0) ? bq : (pz == 1) ? bk : bv;
  int m0 = blockIdx.x * 128;
  int c0 = blockIdx.y * 128;
  int wr = wid >> 1, wc = wid & 1;

  f32x4 zero4 = {0.f, 0.f, 0.f, 0.f};
  f32x4 acc[4][4];
#pragma unroll
  for (int i = 0; i < 4; ++i)
#pragma unroll
    for (int j = 0; j < 4; ++j) acc[i][j] = zero4;

  for (int kt = 0; kt < 4; ++kt) {
#pragma unroll
    for (int it = 0; it < 4; ++it) {
      int li = it * 256 + tid;
      int X = li * 16;
      int row = X >> 7;
      int colb = (X & 127) ^ ((row & 7) << 4);
      gload_lds16((const char*)A + ((size_t)(m0 + row) * CH + kt * 64) * 2 + colb,
                  As + it * 4096 + wid * 1024);
      gload_lds16((const char*)W + ((size_t)(c0 + row) * CH + kt * 64) * 2 + colb,
                  Bs + it * 4096 + wid * 1024);
    }
    __syncthreads();
#pragma unroll
    for (int kk = 0; kk < 2; ++kk) {
      int cb = kk * 64 + ((lane >> 4) << 4);
      short8 af[4], bf[4];
#pragma unroll
      for (int mi = 0; mi < 4; ++mi) {
        int row = wr * 64 + mi * 16 + (lane & 15);
        af[mi] = *(const short8*)(As + row * 128 + (cb ^ ((row & 7) << 4)));
      }
#pragma unroll
      for (int ni = 0; ni < 4; ++ni) {
        int row = wc * 64 + ni * 16 + (lane & 15);
        bf[ni] = *(const short8*)(Bs + row * 128 + (cb ^ ((row & 7) << 4)));
      }
#pragma unroll
      for (int mi = 0; mi < 4; ++mi)
#pragma unroll
        for (int ni = 0; ni < 4; ++ni)
          acc[mi][ni] = __builtin_amdgcn_mfma_f32_16x16x32_bf16(
              af[mi], bf[ni], acc[mi][ni], 0, 0, 0);
    }
    __syncthreads();
  }

  int colbase = c0 + wc * 64;
  int rowbase = m0 + wr * 64;
  if (pz < 2) {
    unsigned short* dst = ((pz == 0) ? q : k) + (size_t)b * NT * CH;
    float scl = (pz == 0) ? QSCALE : 1.0f;
#pragma unroll
    for (int mi = 0; mi < 4; ++mi)
#pragma unroll
      for (int ni = 0; ni < 4; ++ni) {
        int col = colbase + ni * 16 + (lane & 15);
        float bb = bias[col];
        int row0 = rowbase + mi * 16 + ((lane >> 4) << 2);
#pragma unroll
        for (int r = 0; r < 4; ++r)
          dst[(size_t)(row0 + r) * CH + col] = f2bf((acc[mi][ni][r] + bb) * scl);
      }
  } else {
    unsigned short* dst = vt + (size_t)b * CH * NT;
#pragma unroll
    for (int mi = 0; mi < 4; ++mi)
#pragma unroll
      for (int ni = 0; ni < 4; ++ni) {
        int col = colbase + ni * 16 + (lane & 15);
        float bb = bias[col];
        int row0 = rowbase + mi * 16 + ((lane >> 4) << 2);
        ushort4v pk;
#pragma unroll
        for (int r = 0; r < 4; ++r) pk[r] = f2bf(acc[mi][ni][r] + bb);
        *(ushort4v*)(dst + (size_t)col * NT + row0) = pk;
      }
  }
}

// ---------------- flash attention v5: 32x32 MFMA, q=32/wave, K+V in LDS ------
// S^T = K·Q (q = lane&31, in-lane softmax, exp2 domain, scale pre-folded).
// P B-frags = cvt_pk of S regs; V A-frags from LDS (swizzled, conflict-free).
// O^T accumulated [256d][32q]/wave. K,V double-buffered via global_load_lds.
#define STAGEK(kt, buf)                                                        \
  {                                                                            \
    _Pragma("unroll") for (int it = 0; it < 4; ++it) {                         \
      int rowk = it * 8 + wid * 2 + (lane >> 5);                               \
      int colb = ((lane & 31) * 16) ^ ((rowk & 7) << 4);                       \
      gload_lds16((const char*)kb + ((size_t)((kt) + rowk) * CH) * 2 + colb,   \
                  (buf) + it * 4096 + wid * 1024);                             \
    }                                                                          \
  }
#define STAGEV(kt, buf)                                                        \
  {                                                                            \
    _Pragma("unroll") for (int it = 0; it < 4; ++it) {                         \
      int rowv = it * 64 + wid * 16 + (lane >> 2);                             \
      int sic = ((lane & 3) ^ ((lane >> 3) & 3)) << 4;                         \
      gload_lds16((const char*)vb + ((size_t)rowv * NT + (kt)) * 2 + sic,      \
                  (buf) + it * 4096 + wid * 1024);                             \
    }                                                                          \
  }

__global__ __launch_bounds__(256, 2) void attn_kernel(
    const unsigned short* __restrict__ q, const unsigned short* __restrict__ k,
    const unsigned short* __restrict__ vt,
    unsigned short* __restrict__ op0, unsigned short* __restrict__ op1,
    unsigned short* __restrict__ op2, float* __restrict__ ml) {
  __shared__ __align__(1024) char Ks[2][16384];  // [32 kv][256 ch], ^((kv&7)<<4)
  __shared__ __align__(1024) char Vs[2][16384];  // [256 d][32 kv], ^((d&6)<<3)
  int tid = threadIdx.x, lane = tid & 63, wid = tid >> 6;
  int r31 = lane & 31, h2 = lane >> 5;
  int b = blockIdx.z;
  int split = blockIdx.y;
  int q0 = blockIdx.x * QB;
  const unsigned short* qb_ = q + (size_t)b * NT * CH;
  const unsigned short* kb = k + (size_t)b * NT * CH;
  const unsigned short* vb = vt + (size_t)b * CH * NT;

  // Q B-fragments: 32 q-rows x 256 ch per wave (col=q=lane&31, k=h2*8+j)
  int qrow = q0 + wid * 32 + r31;
  short8 qf[16];
#pragma unroll
  for (int st = 0; st < 16; ++st)
    qf[st] = *(const short8*)(qb_ + (size_t)qrow * CH + st * 16 + h2 * 8);

  f32x16 o[8];
#pragma unroll
  for (int i = 0; i < 8; ++i) o[i] = (f32x16){};
  float mrun = -INFINITY, lrun = 0.f;

  int kt0base = split * (TPS * 32);
  STAGEK(kt0base, Ks[0]);
  STAGEV(kt0base, Vs[0]);
  __syncthreads();

  int sw4 = (r31 & 7) << 4;
  int sw3 = (r31 & 6) << 3;
  int oj0 = (8 * h2) ^ sw3, oj1 = (8 * h2 + 16) ^ sw3;
  int oj2 = (8 * h2 + 32) ^ sw3, oj3 = (8 * h2 + 48) ^ sw3;

  union V16 { uint2v p[2]; short8 s8; };
  union PB { unsigned int u[4]; short8 s8; };

  for (int t = 0; t < TPS; ++t) {
    int kt0 = kt0base + t * 32;
    const char* kbase = Ks[t & 1] + r31 * 512 + ((h2 * 16) ^ sw4);
    const char* vL = Vs[t & 1] + r31 * 64;
    if (t + 1 < TPS) {
      STAGEK(kt0 + 32, Ks[(t + 1) & 1]);
      STAGEV(kt0 + 32, Vs[(t + 1) & 1]);
    }

    // S^T = K·Q : 32 kv x 32 q per wave, 16 ch-steps
    f32x16 s = (f32x16){};
    __builtin_amdgcn_s_setprio(1);
#pragma unroll
    for (int st = 0; st < 16; ++st) {
      short8 kf = *(const short8*)((unsigned long long)kbase ^ (unsigned)(st * 32));
      s = __builtin_amdgcn_mfma_f32_32x32x16_bf16(kf, qf[st], s, 0, 0, 0);
    }
    __builtin_amdgcn_s_setprio(0);

    // in-lane online softmax (exp2 domain), kv pair via lane^32
    float mx = fmaxf(s[0], s[1]);
#pragma unroll
    for (int i = 2; i < 16; ++i) mx = fmaxf(mx, s[i]);
    mx = fmaxf(mx, __shfl_xor(mx, 32));
    if (__any(mx - mrun > DEFER_THR)) {
      float mnew = fmaxf(mrun, mx);
      float al = exp2f(mrun - mnew);
      lrun *= al;
      mrun = mnew;
#pragma unroll
      for (int i = 0; i < 8; ++i) o[i] = o[i] * al;
    }
    float rs = 0.f;
#pragma unroll
    for (int i = 0; i < 16; ++i) {
      s[i] = exp2f(s[i] - mrun);
      rs += s[i];
    }
    rs += __shfl_xor(rs, 32);
    lrun += rs;

    // P B-frags straight from S regs (kv-permutation mirrored in V A-frags)
    PB pbA, pbB;
    pbA.u[0] = cvtpk(s[0], s[1]);   pbA.u[1] = cvtpk(s[2], s[3]);
    pbA.u[2] = cvtpk(s[4], s[5]);   pbA.u[3] = cvtpk(s[6], s[7]);
    pbB.u[0] = cvtpk(s[8], s[9]);   pbB.u[1] = cvtpk(s[10], s[11]);
    pbB.u[2] = cvtpk(s[12], s[13]); pbB.u[3] = cvtpk(s[14], s[15]);

    // O^T += V^T·P  (V from LDS, conflict-free b64 reads)
    __builtin_amdgcn_s_setprio(1);
#pragma unroll
    for (int d2 = 0; d2 < 8; ++d2) {
      V16 a1, a2;
      a1.p[0] = *(const uint2v*)(vL + d2 * 2048 + oj0);
      a1.p[1] = *(const uint2v*)(vL + d2 * 2048 + oj1);
      a2.p[0] = *(const uint2v*)(vL + d2 * 2048 + oj2);
      a2.p[1] = *(const uint2v*)(vL + d2 * 2048 + oj3);
      o[d2] = __builtin_amdgcn_mfma_f32_32x32x16_bf16(a1.s8, pbA.s8, o[d2], 0, 0, 0);
      o[d2] = __builtin_amdgcn_mfma_f32_32x32x16_bf16(a2.s8, pbB.s8, o[d2], 0, 0, 0);
    }
    __builtin_amdgcn_s_setprio(0);
    __syncthreads();  // LDS reads done + staged loads drained before next tile
  }

  // store unnormalized partial O^T -> [B,N,C] rows, and (m,l)
  unsigned short* od = ((split == 0) ? op0 : (split == 1) ? op1 : op2) +
                       (size_t)(b * NT + qrow) * CH;
#pragma unroll
  for (int d2 = 0; d2 < 8; ++d2)
#pragma unroll
    for (int m = 0; m < 4; ++m) {
      ushort4v pk;
#pragma unroll
      for (int r = 0; r < 4; ++r) pk[r] = f2bf(o[d2][m * 4 + r]);
      *(ushort4v*)(od + d2 * 32 + m * 8 + h2 * 4) = pk;
    }
  if (lane < 32) {
    float* mlp = ml + ((size_t)(split * NB + b) * NT + q0 + wid * 32 + lane) * 2;
    mlp[0] = mrun;
    mlp[1] = lrun;
  }
}

// ---------------- combine 3 KV-split partials -> oa bf16 [B,N,C] ------------
__global__ __launch_bounds__(256) void combine_kernel(
    const unsigned short* __restrict__ op0, const unsigned short* __restrict__ op1,
    const unsigned short* __restrict__ op2, const float* __restrict__ ml,
    unsigned short* __restrict__ oa) {
  const size_t S = (size_t)NB * NT;
  int g = blockIdx.x * 8 + (threadIdx.x >> 5);
  int c = (threadIdx.x & 31) * 8;
  float m0 = ml[(size_t)g * 2], l0 = ml[(size_t)g * 2 + 1];
  float m1 = ml[(S + g) * 2], l1 = ml[(S + g) * 2 + 1];
  float m2 = ml[(2 * S + g) * 2], l2 = ml[(2 * S + g) * 2 + 1];
  float M = fmaxf(fmaxf(m0, m1), m2);
  float w0 = exp2f(m0 - M), w1 = exp2f(m1 - M), w2 = exp2f(m2 - M);
  float Li = 1.0f / (w0 * l0 + w1 * l1 + w2 * l2);
  w0 *= Li; w1 *= Li; w2 *= Li;
  ushort8v a0 = *(const ushort8v*)(op0 + (size_t)g * CH + c);
  ushort8v a1 = *(const ushort8v*)(op1 + (size_t)g * CH + c);
  ushort8v a2 = *(const ushort8v*)(op2 + (size_t)g * CH + c);
  ushort8v r;
#pragma unroll
  for (int j = 0; j < 8; ++j)
    r[j] = f2bf(w0 * bf2f(a0[j]) + w1 * bf2f(a1[j]) + w2 * bf2f(a2[j]));
  *(ushort8v*)(oa + (size_t)g * CH + c) = r;
}

// ---------------- output projection + bias + residual, out [B,C,N] fp32 ----------------
__global__ __launch_bounds__(256) void oproj_kernel(
    const unsigned short* __restrict__ oa, const unsigned short* __restrict__ wp,
    const float* __restrict__ bp, const float* __restrict__ x1,
    float* __restrict__ outp) {
  __shared__ char As[16384];
  __shared__ char Bs[16384];
  int tid = threadIdx.x;
  int lane = tid & 63, wid = tid >> 6;
  int b = blockIdx.z;
  const unsigned short* A = oa + (size_t)b * NT * CH;
  int m0 = blockIdx.x * 128;
  int c0 = blockIdx.y * 128;
  int wr = wid >> 1, wc = wid & 1;

  f32x4 zero4 = {0.f, 0.f, 0.f, 0.f};
  f32x4 acc[4][4];
#pragma unroll
  for (int i = 0; i < 4; ++i)
#pragma unroll
    for (int j = 0; j < 4; ++j) acc[i][j] = zero4;

  for (int kt = 0; kt < 4; ++kt) {
#pragma unroll
    for (int it = 0; it < 4; ++it) {
      int li = it * 256 + tid;
      int X = li * 16;
      int row = X >> 7;
      int colb = (X & 127) ^ ((row & 7) << 4);
      gload_lds16((const char*)A + ((size_t)(m0 + row) * CH + kt * 64) * 2 + colb,
                  As + it * 4096 + wid * 1024);
      gload_lds16((const char*)wp + ((size_t)(c0 + row) * CH + kt * 64) * 2 + colb,
                  Bs + it * 4096 + wid * 1024);
    }
    __syncthreads();
#pragma unroll
    for (int kk = 0; kk < 2; ++kk) {
      int cb = kk * 64 + ((lane >> 4) << 4);
      short8 af[4], bf[4];
#pragma unroll
      for (int mi = 0; mi < 4; ++mi) {
        int row = wr * 64 + mi * 16 + (lane & 15);
        af[mi] = *(const short8*)(As + row * 128 + (cb ^ ((row & 7) << 4)));
      }
#pragma unroll
      for (int ni = 0; ni < 4; ++ni) {
        int row = wc * 64 + ni * 16 + (lane & 15);
        bf[ni] = *(const short8*)(Bs + row * 128 + (cb ^ ((row & 7) << 4)));
      }
#pragma unroll
      for (int mi = 0; mi < 4; ++mi)
#pragma unroll
        for (int ni = 0; ni < 4; ++ni)
          acc[mi][ni] = __builtin_amdgcn_mfma_f32_16x16x32_bf16(
              af[mi], bf[ni], acc[mi][ni], 0, 0, 0);
    }
    __syncthreads();
  }

  int colbase = c0 + wc * 64;
  int rowbase = m0 + wr * 64;
#pragma unroll
  for (int mi = 0; mi < 4; ++mi)
#pragma unroll
    for (int ni = 0; ni < 4; ++ni) {
      int col = colbase + ni * 16 + (lane & 15);
      float bb = bp[col];
      int row0 = rowbase + mi * 16 + ((lane >> 4) << 2);
      int base = (b * CH + col) * NT + row0;
      float4v xv = *(const float4v*)(x1 + base);
      float4v rs;
#pragma unroll
      for (int r = 0; r < 4; ++r) rs[r] = acc[mi][ni][r] + bb + xv[r];
      *(float4v*)(outp + base) = rs;
    }
}

extern "C" void kernel_launch(void* const* d_in, const int* in_sizes, int n_in,
                              void* d_out, int out_size, void* d_ws, size_t ws_size,
                              hipStream_t stream) {
  (void)in_sizes; (void)n_in; (void)out_size; (void)ws_size;
  const float* x1 = (const float*)d_in[0];
  const float* x2 = (const float*)d_in[1];
  const float* Wq = (const float*)d_in[2];
  const float* bq = (const float*)d_in[3];
  const float* Wk = (const float*)d_in[4];
  const float* bk = (const float*)d_in[5];
  const float* Wv = (const float*)d_in[6];
  const float* bv = (const float*)d_in[7];
  const float* Wp = (const float*)d_in[8];
  const float* bp = (const float*)d_in[9];
  const float* wnq = (const float*)d_in[10];
  const float* bnq = (const float*)d_in[11];
  const float* wnkv = (const float*)d_in[12];
  const float* bnkv = (const float*)d_in[13];
  float* outp = (float*)d_out;

  const size_t TSZ = (size_t)NB * NT * CH;  // 4718592 elements
  unsigned short* xq = (unsigned short*)d_ws;   // -> opart0 after proj
  unsigned short* xkv = xq + TSZ;               // -> opart1 after proj
  unsigned short* qb = xkv + TSZ;
  unsigned short* kbuf = qb + TSZ;
  unsigned short* vtb = kbuf + TSZ;
  unsigned short* oab = vtb + TSZ;              // opart2, combined in-place
  unsigned short* wbf = oab + TSZ;              // 4 x 65536
  float* ml = (float*)(wbf + 4 * 65536);        // KVSPLIT * NB * NT * 2 floats

  wconv_kernel<<<dim3(64, 4), dim3(256), 0, stream>>>(Wq, Wk, Wv, Wp, wbf);
  ln_kernel<<<dim3(36, 8, 2), dim3(256), 0, stream>>>(x1, x2, wnq, bnq, wnkv, bnkv,
                                                      xq, xkv);
  proj_kernel<<<dim3(18, 2, 24), dim3(256), 0, stream>>>(xq, xkv, wbf, bq, bk, bv,
                                                         qb, kbuf, vtb);
  attn_kernel<<<dim3(NT / QB, KVSPLIT, 8), dim3(256), 0, stream>>>(
      qb, kbuf, vtb, xq, xkv, oab, ml);
  combine_kernel<<<dim3(NB * NT / 8), dim3(256), 0, stream>>>(xq, xkv, oab, ml,
                                                              oab);
  oproj_kernel<<<dim3(18, 2, 8), dim3(256), 0, stream>>>(oab, wbf + 3 * 65536, bp,
                                                         x1, outp);
}